// Round 1
// baseline (623.307 us; speedup 1.0000x reference)
//
#include <hip/hip_runtime.h>
#include <hip/hip_bf16.h>

// KoopmanOperators: B=16, N=64, T=8, sd=8, h=128, es=128, ud=32, rd=64, gd=32
// BT = 128, NODES = 8192, PAIRS = 524288
//
// Factorizations (exact affine algebra):
//   h_rel   = relu(P_i - P_j + reb1),            P = s @ reW1
//   pre_rel = enc_rel @ rpW[256:320] + A_i + B_j + rpb,
//             A = enc_obj @ rpW[0:128], B = enc_obj @ rpW[128:256]

constexpr int TT = 8;        // T
constexpr int NN = 64;       // N
constexpr int BTN = 128;     // B*T

// ---------------------------------------------------------------- kernel 1
// per-node encoders. grid 512 blocks x 256 thr, 16 nodes/block
__global__ __launch_bounds__(256) void k_node(
    const float* __restrict__ states,
    const float* __restrict__ sW1, const float* __restrict__ sb1,
    const float* __restrict__ sW2, const float* __restrict__ sb2,
    const float* __restrict__ uW1, const float* __restrict__ ub1,
    const float* __restrict__ uW2, const float* __restrict__ ub2,
    const float* __restrict__ upW, const float* __restrict__ upb,
    const float* __restrict__ reW1,
    const float* __restrict__ rpW,
    float* __restrict__ P_g, float* __restrict__ encobj_g,
    float* __restrict__ obsu_g, float* __restrict__ A_g, float* __restrict__ Bm_g)
{
    const int t   = threadIdx.x;
    const int blk = blockIdx.x;
    const int bt  = blk >> 2;
    const int n0  = (blk & 3) * 16;
    const int b   = bt >> 3, tstep = bt & 7;

    __shared__ float s_s[16][8];
    __shared__ float s_h1[16][128];
    __shared__ float s_hu[16][128];
    __shared__ float s_eo[16][128];
    __shared__ float s_eu[16][32];

    if (t < 128) {
        int n = t >> 3, d = t & 7;
        s_s[n][d] = states[((size_t)(b * NN + (n0 + n)) * TT + tstep) * 8 + d];
    }
    __syncthreads();

    // h1 = relu(s@sW1+sb1), hu = relu(s@uW1+ub1), P = s@reW1 (no bias/relu)
    for (int idx = t; idx < 16 * 128; idx += 256) {
        int n = idx >> 7, c = idx & 127;
        float a1 = sb1[c], au = ub1[c], ap = 0.f;
        #pragma unroll
        for (int d = 0; d < 8; ++d) {
            float sv = s_s[n][d];
            a1 = fmaf(sv, sW1[d * 128 + c], a1);
            au = fmaf(sv, uW1[d * 128 + c], au);
            ap = fmaf(sv, reW1[d * 128 + c], ap);
        }
        s_h1[n][c] = fmaxf(a1, 0.f);
        s_hu[n][c] = fmaxf(au, 0.f);
        P_g[(size_t)(bt * NN + n0 + n) * 128 + c] = ap;
    }
    __syncthreads();

    // enc_obj = relu(h1 @ sW2 + sb2)
    for (int idx = t; idx < 16 * 128; idx += 256) {
        int n = idx >> 7, c = idx & 127;
        float acc = sb2[c];
        #pragma unroll 8
        for (int k = 0; k < 128; ++k) acc = fmaf(s_h1[n][k], sW2[k * 128 + c], acc);
        acc = fmaxf(acc, 0.f);
        s_eo[n][c] = acc;
        encobj_g[(size_t)(bt * NN + n0 + n) * 128 + c] = acc;
    }
    // enc_u = hu @ uW2 + ub2 (no relu)
    for (int idx = t; idx < 16 * 32; idx += 256) {
        int n = idx >> 5, c = idx & 31;
        float acc = ub2[c];
        #pragma unroll 8
        for (int k = 0; k < 128; ++k) acc = fmaf(s_hu[n][k], uW2[k * 32 + c], acc);
        s_eu[n][c] = acc;
    }
    __syncthreads();

    // obs_u = relu([enc_obj, enc_u] @ upW + upb)
    for (int idx = t; idx < 16 * 32; idx += 256) {
        int n = idx >> 5, c = idx & 31;
        float acc = upb[c];
        #pragma unroll 8
        for (int k = 0; k < 128; ++k) acc = fmaf(s_eo[n][k], upW[k * 32 + c], acc);
        #pragma unroll
        for (int k = 0; k < 32; ++k)  acc = fmaf(s_eu[n][k], upW[(128 + k) * 32 + c], acc);
        obsu_g[(size_t)(bt * NN + n0 + n) * 32 + c] = fmaxf(acc, 0.f);
    }
    // A = enc_obj @ rpW[0:128], Bm = enc_obj @ rpW[128:256]
    for (int idx = t; idx < 16 * 64; idx += 256) {
        int n = idx >> 6, c = idx & 63;
        float accA = 0.f, accB = 0.f;
        #pragma unroll 8
        for (int k = 0; k < 128; ++k) {
            float e = s_eo[n][k];
            accA = fmaf(e, rpW[k * 64 + c], accA);
            accB = fmaf(e, rpW[(128 + k) * 64 + c], accB);
        }
        A_g[(size_t)(bt * NN + n0 + n) * 64 + c]  = accA;
        Bm_g[(size_t)(bt * NN + n0 + n) * 64 + c] = accB;
    }
}

// ---------------------------------------------------------------- kernel 2
// pairwise relations. grid 8192 = (bt, i), 256 thr
__global__ __launch_bounds__(256) void k_pair(
    const float* __restrict__ states,
    const float* __restrict__ P_g, const float* __restrict__ A_g,
    const float* __restrict__ Bm_g,
    const float* __restrict__ reb1, const float* __restrict__ reW2,
    const float* __restrict__ reb2,
    const float* __restrict__ rpW, const float* __restrict__ rpb,
    float* __restrict__ relagg_g)
{
    const int t  = threadIdx.x;
    const int bid = blockIdx.x;
    const int bt = bid >> 6, i = bid & 63;
    const int b  = bt >> 3, tstep = bt & 7;

    __shared__ float s_pj[64][128];   // 32 KB
    __shared__ float s_h[64][128];    // 32 KB (reused as t_mat[64][64])
    __shared__ float s_er[64][64];    // 16 KB
    __shared__ float s_pi[128];
    __shared__ float s_ai[64];
    __shared__ float s_b1[128];
    __shared__ float s_s0[64];
    __shared__ float s_s4[64];
    __shared__ float s_red[4][64];
    float* s_t = &s_h[0][0];

    for (int idx = t; idx < 64 * 128; idx += 256) {
        int j = idx >> 7, k = idx & 127;
        s_pj[j][k] = P_g[(size_t)(bt * NN + j) * 128 + k];
    }
    if (t < 128) {
        s_pi[t] = P_g[(size_t)(bt * NN + i) * 128 + t];
        s_b1[t] = reb1[t];
    } else if (t < 192) {
        s_ai[t - 128] = A_g[(size_t)(bt * NN + i) * 64 + (t - 128)];
    } else {
        int j = t - 192;
        const float* sp = &states[((size_t)(b * NN + j) * TT + tstep) * 8];
        s_s0[j] = sp[0];
        s_s4[j] = sp[4];
    }
    __syncthreads();

    // h = relu(P_i - P_j + reb1)
    for (int idx = t; idx < 64 * 128; idx += 256) {
        int j = idx >> 7, k = idx & 127;
        s_h[j][k] = fmaxf(s_pi[k] - s_pj[j][k] + s_b1[k], 0.f);
    }
    __syncthreads();

    const int j0 = (t >> 4) * 4, c0 = (t & 15) * 4;

    // GEMM1: enc_rel = relu(h @ reW2 + reb2)   [64x128]@[128x64]
    {
        float acc[4][4];
        #pragma unroll
        for (int r = 0; r < 4; ++r)
            #pragma unroll
            for (int c = 0; c < 4; ++c) acc[r][c] = reb2[c0 + c];
        #pragma unroll 4
        for (int k = 0; k < 128; ++k) {
            const float4 w = *reinterpret_cast<const float4*>(&reW2[k * 64 + c0]);
            float hv[4];
            #pragma unroll
            for (int r = 0; r < 4; ++r) hv[r] = s_h[j0 + r][k];
            #pragma unroll
            for (int r = 0; r < 4; ++r) {
                acc[r][0] = fmaf(hv[r], w.x, acc[r][0]);
                acc[r][1] = fmaf(hv[r], w.y, acc[r][1]);
                acc[r][2] = fmaf(hv[r], w.z, acc[r][2]);
                acc[r][3] = fmaf(hv[r], w.w, acc[r][3]);
            }
        }
        #pragma unroll
        for (int r = 0; r < 4; ++r)
            #pragma unroll
            for (int c = 0; c < 4; ++c)
                s_er[j0 + r][c0 + c] = fmaxf(acc[r][c], 0.f);
    }
    __syncthreads();

    // GEMM2: t = relu(enc_rel @ rpW_bot + A_i + B_j + rpb) * sel
    {
        float acc[4][4];
        #pragma unroll
        for (int r = 0; r < 4; ++r)
            #pragma unroll
            for (int c = 0; c < 4; ++c) acc[r][c] = rpb[c0 + c];
        #pragma unroll 4
        for (int k = 0; k < 64; ++k) {
            const float4 w = *reinterpret_cast<const float4*>(&rpW[(256 + k) * 64 + c0]);
            float ev[4];
            #pragma unroll
            for (int r = 0; r < 4; ++r) ev[r] = s_er[j0 + r][k];
            #pragma unroll
            for (int r = 0; r < 4; ++r) {
                acc[r][0] = fmaf(ev[r], w.x, acc[r][0]);
                acc[r][1] = fmaf(ev[r], w.y, acc[r][1]);
                acc[r][2] = fmaf(ev[r], w.z, acc[r][2]);
                acc[r][3] = fmaf(ev[r], w.w, acc[r][3]);
            }
        }
        const float s0i = s_s0[i], s4i = s_s4[i];
        #pragma unroll
        for (int r = 0; r < 4; ++r) {
            const int j = j0 + r;
            const float d0 = s0i - s_s0[j];
            const float d4 = s4i - s_s4[j];
            const float sel = (fabsf(d0) > 0.1f || fabsf(d4) > 0.1f) ? 1.f : 0.f;
            const float4 bj = *reinterpret_cast<const float4*>(
                &Bm_g[(size_t)(bt * NN + j) * 64 + c0]);
            float v0 = fmaxf(acc[r][0] + s_ai[c0 + 0] + bj.x, 0.f) * sel;
            float v1 = fmaxf(acc[r][1] + s_ai[c0 + 1] + bj.y, 0.f) * sel;
            float v2 = fmaxf(acc[r][2] + s_ai[c0 + 2] + bj.z, 0.f) * sel;
            float v3 = fmaxf(acc[r][3] + s_ai[c0 + 3] + bj.w, 0.f) * sel;
            s_t[j * 64 + c0 + 0] = v0;
            s_t[j * 64 + c0 + 1] = v1;
            s_t[j * 64 + c0 + 2] = v2;
            s_t[j * 64 + c0 + 3] = v3;
        }
    }
    __syncthreads();

    // rel_agg[i][c] = sum_j t[j][c]
    {
        const int q = t >> 6, c = t & 63;
        float p = 0.f;
        #pragma unroll
        for (int j = 0; j < 16; ++j) p += s_t[(q * 16 + j) * 64 + c];
        s_red[q][c] = p;
    }
    __syncthreads();
    if (t < 64) {
        float v = s_red[0][t] + s_red[1][t] + s_red[2][t] + s_red[3][t];
        relagg_g[(size_t)(bt * NN + i) * 64 + t] = v;
    }
}

// ---------------------------------------------------------------- kernel 3
// composed embedding MLP3. grid 512, 16 nodes/block
__global__ __launch_bounds__(256) void k_comp(
    const float* __restrict__ encobj_g, const float* __restrict__ obsu_g,
    const float* __restrict__ relagg_g,
    const float* __restrict__ cW1, const float* __restrict__ cb1,
    const float* __restrict__ cW2, const float* __restrict__ cb2,
    const float* __restrict__ cW3, const float* __restrict__ cb3,
    float* __restrict__ out)
{
    const int t   = threadIdx.x;
    const int blk = blockIdx.x;
    const int bt  = blk >> 2;
    const int n0  = (blk & 3) * 16;

    __shared__ float s_x[16][224];
    __shared__ float s_h1[16][128];
    __shared__ float s_h2[16][128];

    for (int idx = t; idx < 16 * 224; idx += 256) {
        int n = idx / 224, k = idx - n * 224;
        size_t node = (size_t)(bt * NN + n0 + n);
        float v;
        if (k < 128)      v = encobj_g[node * 128 + k];
        else if (k < 160) v = obsu_g[node * 32 + (k - 128)];
        else              v = relagg_g[node * 64 + (k - 160)];
        s_x[n][k] = v;
    }
    __syncthreads();

    for (int idx = t; idx < 16 * 128; idx += 256) {
        int n = idx >> 7, c = idx & 127;
        float acc = cb1[c];
        #pragma unroll 8
        for (int k = 0; k < 224; ++k) acc = fmaf(s_x[n][k], cW1[k * 128 + c], acc);
        s_h1[n][c] = fmaxf(acc, 0.f);
    }
    __syncthreads();

    for (int idx = t; idx < 16 * 128; idx += 256) {
        int n = idx >> 7, c = idx & 127;
        float acc = cb2[c];
        #pragma unroll 8
        for (int k = 0; k < 128; ++k) acc = fmaf(s_h1[n][k], cW2[k * 128 + c], acc);
        s_h2[n][c] = fmaxf(acc, 0.f);
    }
    __syncthreads();

    for (int idx = t; idx < 16 * 32; idx += 256) {
        int n = idx >> 5, c = idx & 31;
        float acc = cb3[c];
        #pragma unroll 8
        for (int k = 0; k < 128; ++k) acc = fmaf(s_h2[n][k], cW3[k * 32 + c], acc);
        out[(size_t)(bt * NN + n0 + n) * 32 + c] = acc;
    }
}

// ---------------------------------------------------------------- launch
extern "C" void kernel_launch(void* const* d_in, const int* in_sizes, int n_in,
                              void* d_out, int out_size, void* d_ws, size_t ws_size,
                              hipStream_t stream) {
    const float* states = (const float*)d_in[0];
    // d_in[1] = temp (unused)
    const float* sW1  = (const float*)d_in[2];
    const float* sb1  = (const float*)d_in[3];
    const float* sW2  = (const float*)d_in[4];
    const float* sb2  = (const float*)d_in[5];
    const float* uW1  = (const float*)d_in[6];
    const float* ub1  = (const float*)d_in[7];
    const float* uW2  = (const float*)d_in[8];
    const float* ub2  = (const float*)d_in[9];
    const float* upW  = (const float*)d_in[10];
    const float* upb  = (const float*)d_in[11];
    const float* reW1 = (const float*)d_in[12];
    const float* reb1 = (const float*)d_in[13];
    const float* reW2 = (const float*)d_in[14];
    const float* reb2 = (const float*)d_in[15];
    const float* rpW  = (const float*)d_in[16];
    const float* rpb  = (const float*)d_in[17];
    const float* cW1  = (const float*)d_in[18];
    const float* cb1  = (const float*)d_in[19];
    const float* cW2  = (const float*)d_in[20];
    const float* cb2  = (const float*)d_in[21];
    const float* cW3  = (const float*)d_in[22];
    const float* cb3  = (const float*)d_in[23];
    float* out = (float*)d_out;

    float* ws = (float*)d_ws;
    float* P_g      = ws;                      // 8192*128
    float* encobj_g = P_g + 8192 * 128;        // 8192*128
    float* obsu_g   = encobj_g + 8192 * 128;   // 8192*32
    float* A_g      = obsu_g + 8192 * 32;      // 8192*64
    float* Bm_g     = A_g + 8192 * 64;         // 8192*64
    float* relagg_g = Bm_g + 8192 * 64;        // 8192*64

    k_node<<<512, 256, 0, stream>>>(states, sW1, sb1, sW2, sb2, uW1, ub1, uW2, ub2,
                                    upW, upb, reW1, rpW,
                                    P_g, encobj_g, obsu_g, A_g, Bm_g);
    k_pair<<<8192, 256, 0, stream>>>(states, P_g, A_g, Bm_g,
                                     reb1, reW2, reb2, rpW, rpb, relagg_g);
    k_comp<<<512, 256, 0, stream>>>(encobj_g, obsu_g, relagg_g,
                                    cW1, cb1, cW2, cb2, cW3, cb3, out);
}

// Round 2
// 238.272 us; speedup vs baseline: 2.6159x; 2.6159x over previous
//
#include <hip/hip_runtime.h>
#include <hip/hip_bf16.h>

// KoopmanOperators: B=16, N=64, T=8, sd=8, h=128, es=128, ud=32, rd=64, gd=32
// BT = 128, NODES = 8192, PAIRS = 524288
//
// Factorizations (exact affine algebra):
//   h_rel   = relu(P_i - P_j + reb1),            P = s @ reW1
//   pre_rel = enc_rel @ rpW[256:320] + A_i + B_j + rpb,
//             A = enc_obj @ rpW[0:128], B = enc_obj @ rpW[128:256]
//
// k_pair uses mfma_f32_16x16x32_bf16:
//   A-frag: lane l holds A[row][k], row = l&15, k = (l>>4)*8 + e (e=0..7)
//   B-frag: lane l holds B[k][col], col = l&15, k = (l>>4)*8 + e
//   C/D:    lane l reg r holds D[(l>>4)*4 + r][l&15]   (m89-verified)

constexpr int TT = 8;
constexpr int NN = 64;

typedef __bf16 bf16x8 __attribute__((ext_vector_type(8)));
typedef float f32x4 __attribute__((ext_vector_type(4)));

// ---------------------------------------------------------------- k_prep
// pack reW2 / rpW[256:320] into MFMA B-fragment order (bf16), once per launch
__global__ __launch_bounds__(256) void k_prep(
    const float* __restrict__ reW2, const float* __restrict__ rpW,
    __bf16* __restrict__ W2f, __bf16* __restrict__ Wbf)
{
    const int t = threadIdx.x;
    for (int q = t; q < 16 * 512; q += 256) {
        int frag = q >> 9, rem = q & 511, lane = rem >> 3, e = rem & 7;
        int kt = frag >> 2, ct = frag & 3;
        int k = kt * 32 + (lane >> 4) * 8 + e;
        int c = ct * 16 + (lane & 15);
        W2f[q] = (__bf16)reW2[k * 64 + c];
    }
    for (int q = t; q < 8 * 512; q += 256) {
        int frag = q >> 9, rem = q & 511, lane = rem >> 3, e = rem & 7;
        int kt = frag >> 2, ct = frag & 3;   // kt 0..1
        int k = 256 + kt * 32 + (lane >> 4) * 8 + e;
        int c = ct * 16 + (lane & 15);
        Wbf[q] = (__bf16)rpW[k * 64 + c];
    }
}

// ---------------------------------------------------------------- kernel 1
// per-node encoders. grid 512 x 256 thr, 16 nodes/block, 4-way n-blocking
__global__ __launch_bounds__(256) void k_node(
    const float* __restrict__ states,
    const float* __restrict__ sW1, const float* __restrict__ sb1,
    const float* __restrict__ sW2, const float* __restrict__ sb2,
    const float* __restrict__ uW1, const float* __restrict__ ub1,
    const float* __restrict__ uW2, const float* __restrict__ ub2,
    const float* __restrict__ upW, const float* __restrict__ upb,
    const float* __restrict__ reW1,
    const float* __restrict__ rpW,
    float* __restrict__ P_g, float* __restrict__ encobj_g,
    float* __restrict__ obsu_g, float* __restrict__ A_g, float* __restrict__ Bm_g)
{
    const int t   = threadIdx.x;
    const int blk = blockIdx.x;
    const int bt  = blk >> 2;
    const int n0  = (blk & 3) * 16;
    const int b   = bt >> 3, tstep = bt & 7;

    __shared__ float s_s[16][8];
    __shared__ float s_h1[16][128];
    __shared__ float s_hu[16][128];
    __shared__ float s_eo[16][128];
    __shared__ float s_eu[16][32];

    if (t < 128) {
        int n = t >> 3, d = t & 7;
        s_s[n][d] = states[((size_t)(b * NN + (n0 + n)) * TT + tstep) * 8 + d];
    }
    __syncthreads();

    // layer1: h1 = relu(s@sW1+sb1), hu = relu(s@uW1+ub1), P = s@reW1
    for (int idx = t; idx < 512; idx += 256) {
        int g = idx >> 7, c = idx & 127;
        float b1v = sb1[c], buv = ub1[c];
        float a1[4], au[4], ap[4];
        #pragma unroll
        for (int q = 0; q < 4; ++q) { a1[q] = b1v; au[q] = buv; ap[q] = 0.f; }
        #pragma unroll
        for (int d = 0; d < 8; ++d) {
            float w1 = sW1[d * 128 + c], wu = uW1[d * 128 + c], wp = reW1[d * 128 + c];
            #pragma unroll
            for (int q = 0; q < 4; ++q) {
                float sv = s_s[g * 4 + q][d];
                a1[q] = fmaf(sv, w1, a1[q]);
                au[q] = fmaf(sv, wu, au[q]);
                ap[q] = fmaf(sv, wp, ap[q]);
            }
        }
        #pragma unroll
        for (int q = 0; q < 4; ++q) {
            s_h1[g * 4 + q][c] = fmaxf(a1[q], 0.f);
            s_hu[g * 4 + q][c] = fmaxf(au[q], 0.f);
            P_g[(size_t)(bt * NN + n0 + g * 4 + q) * 128 + c] = ap[q];
        }
    }
    __syncthreads();

    // enc_obj = relu(h1 @ sW2 + sb2)
    for (int idx = t; idx < 512; idx += 256) {
        int g = idx >> 7, c = idx & 127;
        float acc[4];
        #pragma unroll
        for (int q = 0; q < 4; ++q) acc[q] = sb2[c];
        #pragma unroll 4
        for (int k = 0; k < 128; ++k) {
            float w = sW2[k * 128 + c];
            #pragma unroll
            for (int q = 0; q < 4; ++q) acc[q] = fmaf(s_h1[g * 4 + q][k], w, acc[q]);
        }
        #pragma unroll
        for (int q = 0; q < 4; ++q) {
            float v = fmaxf(acc[q], 0.f);
            s_eo[g * 4 + q][c] = v;
            encobj_g[(size_t)(bt * NN + n0 + g * 4 + q) * 128 + c] = v;
        }
    }
    // enc_u = hu @ uW2 + ub2 (no relu)
    for (int idx = t; idx < 128; idx += 256) {
        int g = idx >> 5, c = idx & 31;
        float acc[4];
        #pragma unroll
        for (int q = 0; q < 4; ++q) acc[q] = ub2[c];
        #pragma unroll 4
        for (int k = 0; k < 128; ++k) {
            float w = uW2[k * 32 + c];
            #pragma unroll
            for (int q = 0; q < 4; ++q) acc[q] = fmaf(s_hu[g * 4 + q][k], w, acc[q]);
        }
        #pragma unroll
        for (int q = 0; q < 4; ++q) s_eu[g * 4 + q][c] = acc[q];
    }
    __syncthreads();

    // obs_u = relu([enc_obj, enc_u] @ upW + upb)
    for (int idx = t; idx < 128; idx += 256) {
        int g = idx >> 5, c = idx & 31;
        float acc[4];
        #pragma unroll
        for (int q = 0; q < 4; ++q) acc[q] = upb[c];
        #pragma unroll 4
        for (int k = 0; k < 128; ++k) {
            float w = upW[k * 32 + c];
            #pragma unroll
            for (int q = 0; q < 4; ++q) acc[q] = fmaf(s_eo[g * 4 + q][k], w, acc[q]);
        }
        #pragma unroll
        for (int k = 0; k < 32; ++k) {
            float w = upW[(128 + k) * 32 + c];
            #pragma unroll
            for (int q = 0; q < 4; ++q) acc[q] = fmaf(s_eu[g * 4 + q][k], w, acc[q]);
        }
        #pragma unroll
        for (int q = 0; q < 4; ++q)
            obsu_g[(size_t)(bt * NN + n0 + g * 4 + q) * 32 + c] = fmaxf(acc[q], 0.f);
    }
    // A = enc_obj @ rpW[0:128], Bm = enc_obj @ rpW[128:256]
    for (int idx = t; idx < 256; idx += 256) {
        int g = idx >> 6, c = idx & 63;
        float accA[4], accB[4];
        #pragma unroll
        for (int q = 0; q < 4; ++q) { accA[q] = 0.f; accB[q] = 0.f; }
        #pragma unroll 4
        for (int k = 0; k < 128; ++k) {
            float wa = rpW[k * 64 + c];
            float wb = rpW[(128 + k) * 64 + c];
            #pragma unroll
            for (int q = 0; q < 4; ++q) {
                float e = s_eo[g * 4 + q][k];
                accA[q] = fmaf(e, wa, accA[q]);
                accB[q] = fmaf(e, wb, accB[q]);
            }
        }
        #pragma unroll
        for (int q = 0; q < 4; ++q) {
            A_g[(size_t)(bt * NN + n0 + g * 4 + q) * 64 + c]  = accA[q];
            Bm_g[(size_t)(bt * NN + n0 + g * 4 + q) * 64 + c] = accB[q];
        }
    }
}

// ---------------------------------------------------------------- kernel 2
// pairwise relations via MFMA. grid 2048 = (bt, i-group of 4), 4 waves, wave=i
__global__ __launch_bounds__(256, 2) void k_pair(
    const float* __restrict__ states,
    const float* __restrict__ P_g, const float* __restrict__ A_g,
    const float* __restrict__ Bm_g,
    const float* __restrict__ reb1, const float* __restrict__ reb2,
    const float* __restrict__ rpb,
    const __bf16* __restrict__ W2f, const __bf16* __restrict__ Wbf,
    float* __restrict__ relagg_g)
{
    const int t    = threadIdx.x;
    const int lane = t & 63;
    const int w    = t >> 6;
    const int lr   = lane >> 4;   // 0..3
    const int lc   = lane & 15;   // 0..15
    const int bid  = blockIdx.x;
    const int bt   = bid >> 4;
    const int i    = (bid & 15) * 4 + w;
    const int b    = bt >> 3, tstep = bt & 7;

    __shared__ float  s_pj[64 * 128];     // 32 KB, 16B-granule XOR swizzle (f ^ (j&7))
    __shared__ __bf16 s_er[4][64 * 64];   // 32 KB, per-wave, granule XOR (g ^ (j&7))
    __shared__ __bf16 s_bm[64 * 72];      // 9 KB, padded rows
    __shared__ float  s_s0[64], s_s4[64];

    // ---- stage P_j (swizzled), Bm (bf16), s0/s4
    for (int idx = t; idx < 2048; idx += 256) {
        int j = idx >> 5, f = idx & 31;
        const float4 v = *reinterpret_cast<const float4*>(
            &P_g[(size_t)(bt * NN + j) * 128 + f * 4]);
        *reinterpret_cast<float4*>(&s_pj[j * 128 + ((f ^ (j & 7)) << 2)]) = v;
    }
    for (int idx = t; idx < 4096; idx += 256) {
        int j = idx >> 6, c = idx & 63;
        s_bm[j * 72 + c] = (__bf16)Bm_g[(size_t)(bt * NN + j) * 64 + c];
    }
    if (t < 64) {
        const float* sp = &states[((size_t)(b * NN + t) * TT + tstep) * 8];
        s_s0[t] = sp[0];
        s_s4[t] = sp[4];
    }

    // ---- per-wave register prep (global-sourced, overlaps staging)
    // pib[kt] = P_i[k] + reb1[k], k = kt*32 + lr*8 + e
    float4 pib[4][2];
    {
        const float* pi_ptr = &P_g[(size_t)(bt * NN + i) * 128];
        #pragma unroll
        for (int kt = 0; kt < 4; ++kt) {
            int kb = kt * 32 + lr * 8;
            float4 a0 = *reinterpret_cast<const float4*>(pi_ptr + kb);
            float4 a1 = *reinterpret_cast<const float4*>(pi_ptr + kb + 4);
            float4 r0 = *reinterpret_cast<const float4*>(reb1 + kb);
            float4 r1 = *reinterpret_cast<const float4*>(reb1 + kb + 4);
            pib[kt][0].x = a0.x + r0.x; pib[kt][0].y = a0.y + r0.y;
            pib[kt][0].z = a0.z + r0.z; pib[kt][0].w = a0.w + r0.w;
            pib[kt][1].x = a1.x + r1.x; pib[kt][1].y = a1.y + r1.y;
            pib[kt][1].z = a1.z + r1.z; pib[kt][1].w = a1.w + r1.w;
        }
    }
    // weight fragments (pre-packed, coalesced b128)
    bf16x8 w2f[4][4];
    #pragma unroll
    for (int kt = 0; kt < 4; ++kt)
        #pragma unroll
        for (int ct = 0; ct < 4; ++ct)
            w2f[kt][ct] = *reinterpret_cast<const bf16x8*>(
                W2f + ((kt * 4 + ct) * 64 + lane) * 8);
    bf16x8 wbf[2][4];
    #pragma unroll
    for (int kt = 0; kt < 2; ++kt)
        #pragma unroll
        for (int ct = 0; ct < 4; ++ct)
            wbf[kt][ct] = *reinterpret_cast<const bf16x8*>(
                Wbf + ((kt * 4 + ct) * 64 + lane) * 8);
    // biases
    float reb2c[4], aic[4];
    #pragma unroll
    for (int ct = 0; ct < 4; ++ct) {
        reb2c[ct] = reb2[ct * 16 + lc];
        aic[ct]   = A_g[(size_t)(bt * NN + i) * 64 + ct * 16 + lc] + rpb[ct * 16 + lc];
    }

    __syncthreads();

    // sel mask: lane j computes sel[i][j]
    const unsigned long long selm = __ballot(
        fabsf(s_s0[i] - s_s0[lane]) > 0.1f || fabsf(s_s4[i] - s_s4[lane]) > 0.1f);

    __bf16* er = s_er[w];

    // ---- GEMM1: er = relu(h @ reW2 + reb2),  h = relu(pib - P_j)
    #pragma unroll
    for (int jt = 0; jt < 4; ++jt) {
        const int j = jt * 16 + lc;          // A-frag row
        const int jsw = (j & 7);
        bf16x8 af[4];
        #pragma unroll
        for (int kt = 0; kt < 4; ++kt) {
            int f0 = kt * 8 + lr * 2;
            const float4 p0 = *reinterpret_cast<const float4*>(
                &s_pj[j * 128 + ((f0 ^ jsw) << 2)]);
            const float4 p1 = *reinterpret_cast<const float4*>(
                &s_pj[j * 128 + (((f0 + 1) ^ jsw) << 2)]);
            bf16x8 a;
            a[0] = (__bf16)fmaxf(pib[kt][0].x - p0.x, 0.f);
            a[1] = (__bf16)fmaxf(pib[kt][0].y - p0.y, 0.f);
            a[2] = (__bf16)fmaxf(pib[kt][0].z - p0.z, 0.f);
            a[3] = (__bf16)fmaxf(pib[kt][0].w - p0.w, 0.f);
            a[4] = (__bf16)fmaxf(pib[kt][1].x - p1.x, 0.f);
            a[5] = (__bf16)fmaxf(pib[kt][1].y - p1.y, 0.f);
            a[6] = (__bf16)fmaxf(pib[kt][1].z - p1.z, 0.f);
            a[7] = (__bf16)fmaxf(pib[kt][1].w - p1.w, 0.f);
            af[kt] = a;
        }
        #pragma unroll
        for (int ct = 0; ct < 4; ++ct) {
            f32x4 acc = {reb2c[ct], reb2c[ct], reb2c[ct], reb2c[ct]};
            #pragma unroll
            for (int kt = 0; kt < 4; ++kt)
                acc = __builtin_amdgcn_mfma_f32_16x16x32_bf16(af[kt], w2f[kt][ct], acc, 0, 0, 0);
            #pragma unroll
            for (int r = 0; r < 4; ++r) {
                int jj = jt * 16 + lr * 4 + r;
                int c  = ct * 16 + lc;
                er[jj * 64 + ((((c >> 3) ^ (jj & 7)) << 3) | (c & 7))] =
                    (__bf16)fmaxf(acc[r], 0.f);
            }
        }
    }

    // ---- GEMM2 + epilogue: relu(er @ rpWb + A_i + B_j + rpb) * sel, sum over j
    float ragg[4] = {0.f, 0.f, 0.f, 0.f};
    #pragma unroll
    for (int jt = 0; jt < 4; ++jt) {
        const int j = jt * 16 + lc;
        const int jsw = (j & 7);
        bf16x8 a2[2];
        #pragma unroll
        for (int kt = 0; kt < 2; ++kt) {
            int cb = kt * 32 + lr * 8;
            a2[kt] = *reinterpret_cast<const bf16x8*>(
                &er[j * 64 + (((cb >> 3) ^ jsw) << 3)]);
        }
        #pragma unroll
        for (int ct = 0; ct < 4; ++ct) {
            f32x4 acc = {aic[ct], aic[ct], aic[ct], aic[ct]};
            #pragma unroll
            for (int kt = 0; kt < 2; ++kt)
                acc = __builtin_amdgcn_mfma_f32_16x16x32_bf16(a2[kt], wbf[kt][ct], acc, 0, 0, 0);
            #pragma unroll
            for (int r = 0; r < 4; ++r) {
                int jj = jt * 16 + lr * 4 + r;
                float bm = (float)s_bm[jj * 72 + ct * 16 + lc];
                float v = fmaxf(acc[r] + bm, 0.f);
                v = ((selm >> jj) & 1ull) ? v : 0.f;
                ragg[ct] += v;
            }
        }
    }
    // cross-lane reduce over lr groups
    #pragma unroll
    for (int ct = 0; ct < 4; ++ct) {
        ragg[ct] += __shfl_xor(ragg[ct], 16);
        ragg[ct] += __shfl_xor(ragg[ct], 32);
    }
    if (lr == 0) {
        #pragma unroll
        for (int ct = 0; ct < 4; ++ct)
            relagg_g[(size_t)(bt * NN + i) * 64 + ct * 16 + lc] = ragg[ct];
    }
}

// ---------------------------------------------------------------- kernel 3
// composed embedding MLP3. grid 512, 16 nodes/block, 4-way n-blocking
__global__ __launch_bounds__(256) void k_comp(
    const float* __restrict__ encobj_g, const float* __restrict__ obsu_g,
    const float* __restrict__ relagg_g,
    const float* __restrict__ cW1, const float* __restrict__ cb1,
    const float* __restrict__ cW2, const float* __restrict__ cb2,
    const float* __restrict__ cW3, const float* __restrict__ cb3,
    float* __restrict__ out)
{
    const int t   = threadIdx.x;
    const int blk = blockIdx.x;
    const int bt  = blk >> 2;
    const int n0  = (blk & 3) * 16;

    __shared__ float s_x[16][224];
    __shared__ float s_h1[16][128];
    __shared__ float s_h2[16][128];

    for (int idx = t; idx < 16 * 224; idx += 256) {
        int n = idx / 224, k = idx - n * 224;
        size_t node = (size_t)(bt * NN + n0 + n);
        float v;
        if (k < 128)      v = encobj_g[node * 128 + k];
        else if (k < 160) v = obsu_g[node * 32 + (k - 128)];
        else              v = relagg_g[node * 64 + (k - 160)];
        s_x[n][k] = v;
    }
    __syncthreads();

    for (int idx = t; idx < 512; idx += 256) {
        int g = idx >> 7, c = idx & 127;
        float acc[4];
        #pragma unroll
        for (int q = 0; q < 4; ++q) acc[q] = cb1[c];
        #pragma unroll 4
        for (int k = 0; k < 224; ++k) {
            float w = cW1[k * 128 + c];
            #pragma unroll
            for (int q = 0; q < 4; ++q) acc[q] = fmaf(s_x[g * 4 + q][k], w, acc[q]);
        }
        #pragma unroll
        for (int q = 0; q < 4; ++q) s_h1[g * 4 + q][c] = fmaxf(acc[q], 0.f);
    }
    __syncthreads();

    for (int idx = t; idx < 512; idx += 256) {
        int g = idx >> 7, c = idx & 127;
        float acc[4];
        #pragma unroll
        for (int q = 0; q < 4; ++q) acc[q] = cb2[c];
        #pragma unroll 4
        for (int k = 0; k < 128; ++k) {
            float w = cW2[k * 128 + c];
            #pragma unroll
            for (int q = 0; q < 4; ++q) acc[q] = fmaf(s_h1[g * 4 + q][k], w, acc[q]);
        }
        #pragma unroll
        for (int q = 0; q < 4; ++q) s_h2[g * 4 + q][c] = fmaxf(acc[q], 0.f);
    }
    __syncthreads();

    for (int idx = t; idx < 128; idx += 256) {
        int g = idx >> 5, c = idx & 31;
        float acc[4];
        #pragma unroll
        for (int q = 0; q < 4; ++q) acc[q] = cb3[c];
        #pragma unroll 4
        for (int k = 0; k < 128; ++k) {
            float w = cW3[k * 32 + c];
            #pragma unroll
            for (int q = 0; q < 4; ++q) acc[q] = fmaf(s_h2[g * 4 + q][k], w, acc[q]);
        }
        #pragma unroll
        for (int q = 0; q < 4; ++q)
            out[(size_t)(bt * NN + n0 + g * 4 + q) * 32 + c] = acc[q];
    }
}

// ---------------------------------------------------------------- launch
extern "C" void kernel_launch(void* const* d_in, const int* in_sizes, int n_in,
                              void* d_out, int out_size, void* d_ws, size_t ws_size,
                              hipStream_t stream) {
    const float* states = (const float*)d_in[0];
    const float* sW1  = (const float*)d_in[2];
    const float* sb1  = (const float*)d_in[3];
    const float* sW2  = (const float*)d_in[4];
    const float* sb2  = (const float*)d_in[5];
    const float* uW1  = (const float*)d_in[6];
    const float* ub1  = (const float*)d_in[7];
    const float* uW2  = (const float*)d_in[8];
    const float* ub2  = (const float*)d_in[9];
    const float* upW  = (const float*)d_in[10];
    const float* upb  = (const float*)d_in[11];
    const float* reW1 = (const float*)d_in[12];
    const float* reb1 = (const float*)d_in[13];
    const float* reW2 = (const float*)d_in[14];
    const float* reb2 = (const float*)d_in[15];
    const float* rpW  = (const float*)d_in[16];
    const float* rpb  = (const float*)d_in[17];
    const float* cW1  = (const float*)d_in[18];
    const float* cb1  = (const float*)d_in[19];
    const float* cW2  = (const float*)d_in[20];
    const float* cb2  = (const float*)d_in[21];
    const float* cW3  = (const float*)d_in[22];
    const float* cb3  = (const float*)d_in[23];
    float* out = (float*)d_out;

    float* ws = (float*)d_ws;
    float* P_g      = ws;                      // 8192*128
    float* encobj_g = P_g + 8192 * 128;        // 8192*128
    float* obsu_g   = encobj_g + 8192 * 128;   // 8192*32
    float* A_g      = obsu_g + 8192 * 32;      // 8192*64
    float* Bm_g     = A_g + 8192 * 64;         // 8192*64
    float* relagg_g = Bm_g + 8192 * 64;        // 8192*64
    __bf16* W2f = (__bf16*)(relagg_g + 8192 * 64);  // 16*512 bf16
    __bf16* Wbf = W2f + 16 * 512;                   // 8*512 bf16

    k_prep<<<1, 256, 0, stream>>>(reW2, rpW, W2f, Wbf);
    k_node<<<512, 256, 0, stream>>>(states, sW1, sb1, sW2, sb2, uW1, ub1, uW2, ub2,
                                    upW, upb, reW1, rpW,
                                    P_g, encobj_g, obsu_g, A_g, Bm_g);
    k_pair<<<2048, 256, 0, stream>>>(states, P_g, A_g, Bm_g,
                                     reb1, reb2, rpb, W2f, Wbf, relagg_g);
    k_comp<<<512, 256, 0, stream>>>(encobj_g, obsu_g, relagg_g,
                                    cW1, cb1, cW2, cb2, cW3, cb3, out);
}